// Round 1
// baseline (1227.646 us; speedup 1.0000x reference)
//
#include <hip/hip_runtime.h>
#include <cmath>

namespace {

constexpr int kWin = 100;
constexpr int kNin = 700;
constexpr int kMaxD = 5;
constexpr int kT = kWin + kMaxD;  // 105

// Transposed-weight offsets (floats) inside d_ws.
constexpr size_t OFF1 = 0;        // WT1 [700][512]
constexpr size_t OFF2 = 358400;   // WT2 [512][256]
constexpr size_t OFF3 = 489472;   // WT3 [256][128]
constexpr size_t OFF4 = 522240;   // WT4 [128][256]
constexpr size_t OFF5 = 555008;   // WT5 [256][512]
constexpr size_t OFF6 = 686080;   // WT6 [512][700]

__global__ void transpose_k(const float* __restrict__ src, float* __restrict__ dst,
                            int H, int K) {
  int idx = blockIdx.x * blockDim.x + threadIdx.x;
  if (idx < H * K) {
    int h = idx / K;
    int k = idx - h * K;
    dst[k * H + h] = src[idx];  // dst[K][H] = src[H][K]^T
  }
}

// Deterministic ordered compaction of per-slot predicates into an index list.
// Each 256-thread half-block builds its own list. Two __syncthreads, both
// reached uniformly by all 512 threads.
template <int NS>
__device__ __forceinline__ int compact_list(const bool* pred, int* dstList,
                                            int (*woff)[3][4], int half, int ht,
                                            int lane, int wv) {
  unsigned long long mask[NS];
#pragma unroll
  for (int c = 0; c < NS; ++c) {
    mask[c] = __ballot(pred[c]);
    if (lane == 0) woff[half][c][wv] = (int)__popcll(mask[c]);
  }
  __syncthreads();
  const unsigned long long lt = (1ull << lane) - 1ull;
  int base = 0;
#pragma unroll
  for (int c = 0; c < NS; ++c) {
    const int w0 = woff[half][c][0];
    const int w1 = woff[half][c][1];
    const int w2 = woff[half][c][2];
    const int w3 = woff[half][c][3];
    int off = base;
    if (wv > 0) off += w0;
    if (wv > 1) off += w1;
    if (wv > 2) off += w2;
    off += (int)__popcll(mask[c] & lt);
    if (pred[c]) dstList[off] = c * 256 + ht;
    base += w0 + w1 + w2 + w3;
  }
  __syncthreads();
  return base;
}

// One LIF layer for one batch row (processed by a 256-thread half-block).
// mem_new = mem*alpha + sum of active Wt columns (f64); spike = mem_new > 0.3;
// mem = (mem_new < 0.3) ? mem_new : 0.   (the (1-o_spike) factor is provably
// redundant because the hard reset already zeroed spiking neurons)
template <int K, int H, bool BUILD>
__device__ __forceinline__ int layer_step(const float* __restrict__ WT,
                                          const int* __restrict__ listIn, int cntIn,
                                          double* mem, double alpha,
                                          int* listOut, int (*woff)[3][4],
                                          int half, int ht, int lane, int wv,
                                          float* outRow, bool writeOut) {
  constexpr int NS = (H + 255) / 256;
  double acc[NS];
#pragma unroll
  for (int s = 0; s < NS; ++s) acc[s] = 0.0;

  // Sparse column-sum, unrolled x4 for load ILP. Strict-IEEE order (increasing j).
  int j = 0;
  const int cnt4 = cntIn & ~3;
  for (; j < cnt4; j += 4) {
    const int k0 = listIn[j + 0];
    const int k1 = listIn[j + 1];
    const int k2 = listIn[j + 2];
    const int k3 = listIn[j + 3];
    const float* p0 = WT + (size_t)k0 * H;
    const float* p1 = WT + (size_t)k1 * H;
    const float* p2 = WT + (size_t)k2 * H;
    const float* p3 = WT + (size_t)k3 * H;
#pragma unroll
    for (int s = 0; s < NS; ++s) {
      const int h = s * 256 + ht;
      if (h < H) {
        const float f0 = p0[h];
        const float f1 = p1[h];
        const float f2 = p2[h];
        const float f3 = p3[h];
        acc[s] += (double)f0;
        acc[s] += (double)f1;
        acc[s] += (double)f2;
        acc[s] += (double)f3;
      }
    }
  }
  for (; j < cntIn; ++j) {
    const int k0 = listIn[j];
    const float* p0 = WT + (size_t)k0 * H;
#pragma unroll
    for (int s = 0; s < NS; ++s) {
      const int h = s * 256 + ht;
      if (h < H) acc[s] += (double)p0[h];
    }
  }

  bool pred[NS];
#pragma unroll
  for (int s = 0; s < NS; ++s) {
    const int h = s * 256 + ht;
    if (h < H) {
      const double m = mem[s] * alpha + acc[s];
      const bool sp = (m > 0.3);
      pred[s] = sp;
      mem[s] = (m < 0.3) ? m : 0.0;
      if (!BUILD) {
        if (writeOut) outRow[h] = sp ? 1.0f : 0.0f;
      }
    } else {
      pred[s] = false;
    }
  }
  if (BUILD) {
    return compact_list<NS>(pred, listOut, woff, half, ht, lane, wv);
  }
  return 0;
}

// 256 blocks x 512 threads. Block b owns batch rows 2b (threads 0..255) and
// 2b+1 (threads 256..511). Entire 105-step recurrence runs in one kernel,
// no inter-workgroup communication.
__global__ __launch_bounds__(512) void snn_main(const float* __restrict__ x,
                                                const float* __restrict__ ws,
                                                float* __restrict__ out) {
  const int tid = threadIdx.x;
  const int half = tid >> 8;
  const int ht = tid & 255;
  const int lane = tid & 63;
  const int wv = (tid >> 6) & 3;
  const int row = blockIdx.x * 2 + half;

  const float* WT1 = ws + OFF1;
  const float* WT2 = ws + OFF2;
  const float* WT3 = ws + OFF3;
  const float* WT4 = ws + OFF4;
  const float* WT5 = ws + OFF5;
  const float* WT6 = ws + OFF6;

  __shared__ int lists[2][2][704];  // [pingpong][half][idx]
  __shared__ int woff[2][3][4];     // [half][chunk][wave]

  // Per-thread membrane state (f64), slot s covers neuron h = s*256 + ht.
  double m1[2] = {0.0, 0.0};
  double m2[1] = {0.0};
  double m3[1] = {0.0};
  double m4[1] = {0.0};
  double m5[2] = {0.0, 0.0};
  double m6[3] = {0.0, 0.0, 0.0};

  const double alpha = exp(-1.0 / 3.0);

  const float* xRow = x + (size_t)row * kWin * kNin;
  float* outRowBase = out + (size_t)row * kWin * kNin;

  for (int t = 0; t < kT; ++t) {
    const bool live = (t >= kMaxD);
    // Build input active list from x (first kMaxD steps are zero-padded).
    int cntIn;
    {
      bool pred[3];
      if (live) {
        const float* xr = xRow + (size_t)(t - kMaxD) * kNin;
#pragma unroll
        for (int s = 0; s < 3; ++s) {
          const int h = s * 256 + ht;
          pred[s] = (h < kNin) ? (xr[h] != 0.0f) : false;
        }
      } else {
        pred[0] = pred[1] = pred[2] = false;
      }
      cntIn = compact_list<3>(pred, lists[0][half], woff, half, ht, lane, wv);
    }

    const int c1 = layer_step<700, 512, true>(WT1, lists[0][half], cntIn, m1, alpha,
                                              lists[1][half], woff, half, ht, lane, wv,
                                              nullptr, false);
    const int c2 = layer_step<512, 256, true>(WT2, lists[1][half], c1, m2, alpha,
                                              lists[0][half], woff, half, ht, lane, wv,
                                              nullptr, false);
    const int c3 = layer_step<256, 128, true>(WT3, lists[0][half], c2, m3, alpha,
                                              lists[1][half], woff, half, ht, lane, wv,
                                              nullptr, false);
    const int c4 = layer_step<128, 256, true>(WT4, lists[1][half], c3, m4, alpha,
                                              lists[0][half], woff, half, ht, lane, wv,
                                              nullptr, false);
    const int c5 = layer_step<256, 512, true>(WT5, lists[0][half], c4, m5, alpha,
                                              lists[1][half], woff, half, ht, lane, wv,
                                              nullptr, false);
    float* outRow = outRowBase + (size_t)(live ? (t - kMaxD) : 0) * kNin;
    layer_step<512, 700, false>(WT6, lists[1][half], c5, m6, alpha,
                                nullptr, woff, half, ht, lane, wv,
                                outRow, live);
  }
}

}  // namespace

extern "C" void kernel_launch(void* const* d_in, const int* in_sizes, int n_in,
                              void* d_out, int out_size, void* d_ws, size_t ws_size,
                              hipStream_t stream) {
  const float* x = (const float*)d_in[0];
  float* ws = (float*)d_ws;
  float* out = (float*)d_out;

  // Transpose all weights into workspace: dst[K][H] = W[H][K]^T.
  struct TK { int H, K; size_t off; int idx; };
  const TK tk[6] = {
      {512, 700, OFF1, 1},  // W_ih1
      {256, 512, OFF2, 2},  // W_h1h2
      {128, 256, OFF3, 3},  // W_h2h3
      {256, 128, OFF4, 4},  // W_h3h2
      {512, 256, OFF5, 5},  // W_h2h1
      {700, 512, OFF6, 6},  // W_h1o
  };
  for (int i = 0; i < 6; ++i) {
    const int n = tk[i].H * tk[i].K;
    transpose_k<<<(n + 255) / 256, 256, 0, stream>>>(
        (const float*)d_in[tk[i].idx], ws + tk[i].off, tk[i].H, tk[i].K);
  }

  snn_main<<<256, 512, 0, stream>>>(x, ws, out);
}

// Round 2
// 1124.792 us; speedup vs baseline: 1.0914x; 1.0914x over previous
//
#include <hip/hip_runtime.h>
#include <cmath>

namespace {

constexpr int kWin = 100;
constexpr int kNin = 700;

// Transposed-weight offsets (floats) inside d_ws.
constexpr size_t OFF1 = 0;        // WT1 [700][512]
constexpr size_t OFF2 = 358400;   // WT2 [512][256]
constexpr size_t OFF3 = 489472;   // WT3 [256][128]
constexpr size_t OFF4 = 522240;   // WT4 [128][256]
constexpr size_t OFF5 = 555008;   // WT5 [256][512]
constexpr size_t OFF6 = 686080;   // WT6 [512][700]
constexpr size_t OFF_END = 1044480;          // floats used by weights
constexpr size_t XM_OFF_U64 = OFF_END / 2;   // u64 index into ws for xmasks
// xmask layout: [B=512][T=100][12] u64 words (11 used + 1 pad, always written)

__global__ void transpose_k(const float* __restrict__ src, float* __restrict__ dst,
                            int H, int K) {
  int idx = blockIdx.x * blockDim.x + threadIdx.x;
  if (idx < H * K) {
    int h = idx / K;
    int k = idx - h * K;
    dst[k * H + h] = src[idx];  // dst[K][H] = src[H][K]^T
  }
}

// Build input spike bitmasks: one block per (row, t), 256 threads.
// Word layout: word w covers input neurons h in [w*64, w*64+64), bit = h%64.
__global__ __launch_bounds__(256) void xmask_k(const float* __restrict__ x,
                                               unsigned long long* __restrict__ xm) {
  const int bid = blockIdx.x;  // row * 100 + t
  const int tid = threadIdx.x;
  const int lane = tid & 63;
  const int wv = tid >> 6;  // 0..3
  const float* xr = x + (size_t)bid * kNin;
  unsigned long long* dst = xm + (size_t)bid * 12;
#pragma unroll
  for (int s = 0; s < 3; ++s) {
    const int h = s * 256 + tid;
    const bool p = (h < kNin) ? (xr[h] != 0.0f) : false;
    const unsigned long long b = __ballot(p);
    if (lane == 0) dst[s * 4 + wv] = b;  // s=2,wv=3 writes pad word 11 (= 0)
  }
}

// One LIF layer. 1024 threads handle one batch row: kp = tid>>8 splits the
// active-column sum 4 ways (32-bit mask chunks, c % 4 == kp); ht = tid&255
// covers the output neurons (h = s*256 + ht). Partials combined via LDS in
// the fixed order ((p0+p1)+p2)+p3 -> deterministic f64.
// mem_new = mem*alpha + sum(active WT columns); spike = mem_new > 0.3;
// mem = (mem_new < 0.3) ? mem_new : 0.  ((1-o_spike) factor is redundant:
// the hard reset already zeroed spiking neurons; VRESET = 0.)
template <int K, int H, bool BUILD, typename FCh>
__device__ __forceinline__ void lif(const float* __restrict__ WT, FCh&& chunk,
                                    double* mem, unsigned long long* mOut,
                                    double (*part)[3][256],  // [kp][s][ht]
                                    float* outRow,
                                    int kp, int ht, int lane, int wv4,
                                    double alpha) {
  constexpr int NS = (H + 255) / 256;
  constexpr int NC = (K + 31) / 32;  // 32-bit mask chunks
  double acc[NS];
#pragma unroll
  for (int s = 0; s < NS; ++s) acc[s] = 0.0;

  for (int c = kp; c < NC; c += 4) {
    unsigned m = __builtin_amdgcn_readfirstlane(chunk(c));
    const float* __restrict__ cbase = WT + (size_t)c * 32 * H;
    const int cnt = __builtin_popcount(m);
    int i = 0;
    for (; i + 4 <= cnt; i += 4) {
      const int b0 = __builtin_ctz(m); m &= m - 1;
      const int b1 = __builtin_ctz(m); m &= m - 1;
      const int b2 = __builtin_ctz(m); m &= m - 1;
      const int b3 = __builtin_ctz(m); m &= m - 1;
      const float* p0 = cbase + b0 * H;
      const float* p1 = cbase + b1 * H;
      const float* p2 = cbase + b2 * H;
      const float* p3 = cbase + b3 * H;
#pragma unroll
      for (int s = 0; s < NS; ++s) {
        constexpr bool kFull = true;  // placeholder for unroll clarity
        (void)kFull;
        const int h = s * 256 + ht;
        if ((s + 1) * 256 <= H || h < H) {
          const float f0 = p0[h];
          const float f1 = p1[h];
          const float f2 = p2[h];
          const float f3 = p3[h];
          acc[s] += (double)f0;
          acc[s] += (double)f1;
          acc[s] += (double)f2;
          acc[s] += (double)f3;
        }
      }
    }
    for (; i < cnt; ++i) {
      const int b0 = __builtin_ctz(m); m &= m - 1;
      const float* p0 = cbase + b0 * H;
#pragma unroll
      for (int s = 0; s < NS; ++s) {
        const int h = s * 256 + ht;
        if ((s + 1) * 256 <= H || h < H) acc[s] += (double)p0[h];
      }
    }
  }

#pragma unroll
  for (int s = 0; s < NS; ++s) part[kp][s][ht] = acc[s];
  __syncthreads();  // SYNC1: partials ready

  bool pred[NS];
#pragma unroll
  for (int s = 0; s < NS; ++s) {
    const int h = s * 256 + ht;
    if ((s + 1) * 256 <= H || h < H) {
      const double p01 = part[0][s][ht] + part[1][s][ht];
      const double tot = (p01 + part[2][s][ht]) + part[3][s][ht];
      const double mm = mem[s] * alpha + tot;
      pred[s] = (mm > 0.3);
      mem[s] = (mm < 0.3) ? mm : 0.0;
      if (!BUILD) {
        if (kp == s) outRow[h] = pred[s] ? 1.0f : 0.0f;  // slot s stored by kp==s
      }
    } else {
      pred[s] = false;
    }
  }
  if (BUILD) {
#pragma unroll
    for (int s = 0; s < NS; ++s) {
      const unsigned long long b = __ballot(pred[s]);
      if (kp == 0 && lane == 0) mOut[s * 4 + wv4] = b;
    }
    __syncthreads();  // SYNC2: next layer's mask ready
  }
}

// 512 blocks x 1024 threads, one batch row per block. Steps 0..4 of the
// reference (zero-padded input) provably keep all state at 0, so we run only
// the 100 live steps.
__global__ __launch_bounds__(1024, 8) void snn_main(
    const float* __restrict__ wsf, const unsigned long long* __restrict__ xmask,
    float* __restrict__ out) {
  const int tid = threadIdx.x;
  const int kp = tid >> 8;         // 0..3
  const int ht = tid & 255;
  const int lane = tid & 63;
  const int wv4 = (tid >> 6) & 3;  // wave index within kp group
  const int row = blockIdx.x;

  const float* WT1 = wsf + OFF1;
  const float* WT2 = wsf + OFF2;
  const float* WT3 = wsf + OFF3;
  const float* WT4 = wsf + OFF4;
  const float* WT5 = wsf + OFF5;
  const float* WT6 = wsf + OFF6;

  __shared__ unsigned long long mk[2][12];
  __shared__ double parts[2][4][3][256];  // [pingpong][kp][s][ht]

  // Per-thread membrane state (f64); slot s covers neuron h = s*256 + ht.
  double m1[2] = {0.0, 0.0};
  double m2[1] = {0.0};
  double m3[1] = {0.0};
  double m4[1] = {0.0};
  double m5[2] = {0.0, 0.0};
  double m6[3] = {0.0, 0.0, 0.0};

  const double alpha = exp(-1.0 / 3.0);

  const unsigned long long* xmRow = xmask + (size_t)row * kWin * 12;
  float* outRowBase = out + (size_t)row * kWin * kNin;

  for (int t = 0; t < kWin; ++t) {
    const unsigned* xm32 = (const unsigned*)(xmRow + (size_t)t * 12);
    const unsigned* mk0 = (const unsigned*)&mk[0][0];
    const unsigned* mk1 = (const unsigned*)&mk[1][0];

    lif<700, 512, true>(WT1, [&](int c) { return xm32[c]; }, m1, mk[0],
                        parts[0], nullptr, kp, ht, lane, wv4, alpha);
    lif<512, 256, true>(WT2, [&](int c) { return mk0[c]; }, m2, mk[1],
                        parts[1], nullptr, kp, ht, lane, wv4, alpha);
    lif<256, 128, true>(WT3, [&](int c) { return mk1[c]; }, m3, mk[0],
                        parts[0], nullptr, kp, ht, lane, wv4, alpha);
    lif<128, 256, true>(WT4, [&](int c) { return mk0[c]; }, m4, mk[1],
                        parts[1], nullptr, kp, ht, lane, wv4, alpha);
    lif<256, 512, true>(WT5, [&](int c) { return mk1[c]; }, m5, mk[0],
                        parts[0], nullptr, kp, ht, lane, wv4, alpha);
    float* outRow = outRowBase + (size_t)t * kNin;
    lif<512, 700, false>(WT6, [&](int c) { return mk0[c]; }, m6, nullptr,
                         parts[1], outRow, kp, ht, lane, wv4, alpha);
  }
}

}  // namespace

extern "C" void kernel_launch(void* const* d_in, const int* in_sizes, int n_in,
                              void* d_out, int out_size, void* d_ws, size_t ws_size,
                              hipStream_t stream) {
  const float* x = (const float*)d_in[0];
  float* ws = (float*)d_ws;
  unsigned long long* xm = (unsigned long long*)d_ws + XM_OFF_U64;
  float* out = (float*)d_out;

  // Transpose all weights into workspace: dst[K][H] = W[H][K]^T.
  struct TK { int H, K; size_t off; int idx; };
  const TK tk[6] = {
      {512, 700, OFF1, 1},  // W_ih1
      {256, 512, OFF2, 2},  // W_h1h2
      {128, 256, OFF3, 3},  // W_h2h3
      {256, 128, OFF4, 4},  // W_h3h2
      {512, 256, OFF5, 5},  // W_h2h1
      {700, 512, OFF6, 6},  // W_h1o
  };
  for (int i = 0; i < 6; ++i) {
    const int n = tk[i].H * tk[i].K;
    transpose_k<<<(n + 255) / 256, 256, 0, stream>>>(
        (const float*)d_in[tk[i].idx], ws + tk[i].off, tk[i].H, tk[i].K);
  }

  // Precompute input spike bitmasks for all (row, t).
  xmask_k<<<512 * kWin, 256, 0, stream>>>(x, xm);

  snn_main<<<512, 1024, 0, stream>>>(ws, xm, out);
}